// Round 1
// baseline (495.365 us; speedup 1.0000x reference)
//
#include <hip/hip_runtime.h>

#define CUT0 20000
#define CUT1 60000
#define D    1024
#define D1   256
#define D2   64
#define NTOK 32768

// ws layout:
//   int   cnt[2]            @ 0      (n1, n2)
//   int   list1[NTOK]       @ 256 B
//   int   list2[NTOK]
//   float w1T[D1*D]         (transposed: w1T[k*D + d] = w1[d*D1 + k])
//   float w2T[D2*D]
// total ~1.5 MB

__global__ void k_init(int* cnt) {
    if (threadIdx.x < 2) cnt[threadIdx.x] = 0;
}

__global__ __launch_bounds__(256) void k_prep(
        const int* __restrict__ ids,
        const float* __restrict__ emb0,
        const float* __restrict__ w1,
        const float* __restrict__ w2,
        float* __restrict__ out,
        int* cnt, int* list1, int* list2,
        float* __restrict__ w1T, float* __restrict__ w2T) {
    int bid = blockIdx.x, tid = threadIdx.x;
    if (bid < NTOK) {
        int id = ids[bid];
        if (id < CUT0) {
            // cluster 0: direct row copy, 256 threads x float4 = 4 KB
            const float4* src = (const float4*)(emb0 + (size_t)id * D);
            float4* dst = (float4*)(out + (size_t)bid * D);
            dst[tid] = src[tid];
        } else if (tid == 0) {
            if (id < CUT1) { int p = atomicAdd(cnt + 0, 1); list1[p] = bid; }
            else           { int p = atomicAdd(cnt + 1, 1); list2[p] = bid; }
        }
    } else {
        // transpose w1 (1024x256 -> 256x1024) then w2 (1024x64 -> 64x1024)
        int i = (bid - NTOK) * 256 + tid;
        if (i < D1 * D) {
            int k = i >> 10, d = i & (D - 1);
            w1T[i] = w1[d * D1 + k];
        } else {
            int j = i - D1 * D;      // j < D2*D by grid sizing
            int k = j >> 10, d = j & (D - 1);
            w2T[j] = w2[d * D2 + k];
        }
    }
}

// One kernel for both projected clusters.
// Block = 256 threads. Tile = 32 tokens x 256 outputs (dd selects d-quarter).
// blocks [0,4096)   : cluster 1 (K=256)
// blocks [4096,8192): cluster 2 (K=64)
__global__ __launch_bounds__(256) void k_gemm(
        const int* __restrict__ ids,
        const float* __restrict__ emb1,
        const float* __restrict__ emb2,
        const float* __restrict__ b1,
        const float* __restrict__ b2,
        float* __restrict__ out,
        const int* __restrict__ cnt,
        const int* __restrict__ list1,
        const int* __restrict__ list2,
        const float* __restrict__ w1T,
        const float* __restrict__ w2T) {
    // As[k][i], pad stride 36 so float4 groups stay 16B-aligned (144 = 16*9)
    __shared__ float As[D1 * 36];
    __shared__ int toks[32];
    __shared__ int lidx[32];

    int bid = blockIdx.x, tid = threadIdx.x;
    bool c1 = bid < 4096;
    int bb = c1 ? bid : bid - 4096;
    int dd = bb & 3, tt = bb >> 2;
    int n = c1 ? cnt[0] : cnt[1];
    int base = tt * 32;
    if (base >= n) return;
    int nt = min(32, n - base);

    const int* list = c1 ? list1 : list2;
    if (tid < nt) {
        int tok = list[base + tid];
        toks[tid] = tok;
        lidx[tid] = ids[tok] - (c1 ? CUT0 : CUT1);
    }
    __syncthreads();

    if (c1) {
        // stage 32 rows of 256 floats: thread tid loads element k=tid of row i
        for (int i = 0; i < 32; i++) {
            float v = (i < nt) ? emb1[(size_t)lidx[i] * D1 + tid] : 0.f;
            As[tid * 36 + i] = v;
        }
    } else {
        // rows of 64 floats: 4 rows per iteration
        int k = tid & 63, ii = tid >> 6;
        for (int it = 0; it < 8; it++) {
            int i = it * 4 + ii;
            float v = (i < nt) ? emb2[(size_t)lidx[i] * D2 + k] : 0.f;
            As[k * 36 + i] = v;
        }
    }
    __syncthreads();

    int d = dd * 256 + tid;
    float acc[32];
#pragma unroll
    for (int i = 0; i < 32; i++) acc[i] = 0.f;

    if (c1) {
        for (int k = 0; k < D1; k++) {
            float b = w1T[k * D + d];
#pragma unroll
            for (int i = 0; i < 32; i++) acc[i] += As[k * 36 + i] * b;
        }
    } else {
        for (int k = 0; k < D2; k++) {
            float b = w2T[k * D + d];
#pragma unroll
            for (int i = 0; i < 32; i++) acc[i] += As[k * 36 + i] * b;
        }
    }

    float bias = c1 ? b1[d] : b2[d];
    for (int i = 0; i < nt; i++)
        out[(size_t)toks[i] * D + d] = acc[i] + bias;
}

extern "C" void kernel_launch(void* const* d_in, const int* in_sizes, int n_in,
                              void* d_out, int out_size, void* d_ws, size_t ws_size,
                              hipStream_t stream) {
    const int*   ids  = (const int*)d_in[0];
    const float* emb0 = (const float*)d_in[1];
    const float* emb1 = (const float*)d_in[2];
    const float* emb2 = (const float*)d_in[3];
    const float* w1   = (const float*)d_in[4];
    const float* b1   = (const float*)d_in[5];
    const float* w2   = (const float*)d_in[6];
    const float* b2   = (const float*)d_in[7];
    float* out = (float*)d_out;

    int* cnt   = (int*)d_ws;
    int* list1 = cnt + 64;            // 256 B offset
    int* list2 = list1 + NTOK;
    float* w1T = (float*)(list2 + NTOK);
    float* w2T = w1T + D1 * D;

    hipLaunchKernelGGL(k_init, dim3(1), dim3(64), 0, stream, cnt);
    // 32768 token blocks + 1280 transpose blocks (327680 elements / 256)
    hipLaunchKernelGGL(k_prep, dim3(NTOK + 1280), dim3(256), 0, stream,
                       ids, emb0, w1, w2, out, cnt, list1, list2, w1T, w2T);
    hipLaunchKernelGGL(k_gemm, dim3(8192), dim3(256), 0, stream,
                       ids, emb1, emb2, b1, b2, out, cnt, list1, list2, w1T, w2T);
}

// Round 3
// 147.595 us; speedup vs baseline: 3.3562x; 3.3562x over previous
//
#include <hip/hip_runtime.h>

#define CUT0 20000
#define CUT1 60000
#define D    1024
#define D1   256
#define D2   64
#define NTOK 32768

// ws layout:
//   int      cnt[3]            (n0, n1, n2)
//   unsigned list0[NTOK], list1[NTOK], list2[NTOK]  packed (tok<<17)|local_idx (UNSIGNED!)
//   float    w1T[D1*D]         w1T[k*D+d] = w1[d*D1+k]
//   float    w2T[D2*D]

__global__ void k_init(int* cnt) {
    if (threadIdx.x < 3) cnt[threadIdx.x] = 0;
}

__global__ __launch_bounds__(256) void k_classify(
        const int* __restrict__ ids,
        const float* __restrict__ w1,
        const float* __restrict__ w2,
        int* cnt, unsigned* list0, unsigned* list1, unsigned* list2,
        float* __restrict__ w1T, float* __restrict__ w2T) {
    int bid = blockIdx.x, tid = threadIdx.x;
    if (bid < NTOK / 256) {
        unsigned t = bid * 256 + tid;
        int id = ids[t];
        int lane = tid & 63;
        unsigned long long lanebit = 1ull << lane;
        int c = (id < CUT0) ? 0 : (id < CUT1 ? 1 : 2);
        {
            unsigned long long m = __ballot(c == 0);
            if (m) {
                int base = 0;
                if (lane == 0) base = atomicAdd(cnt + 0, __popcll(m));
                base = __shfl(base, 0);
                if (c == 0) list0[base + __popcll(m & (lanebit - 1))] = (t << 17) | (unsigned)id;
            }
        }
        {
            unsigned long long m = __ballot(c == 1);
            if (m) {
                int base = 0;
                if (lane == 0) base = atomicAdd(cnt + 1, __popcll(m));
                base = __shfl(base, 0);
                if (c == 1) list1[base + __popcll(m & (lanebit - 1))] = (t << 17) | (unsigned)(id - CUT0);
            }
        }
        {
            unsigned long long m = __ballot(c == 2);
            if (m) {
                int base = 0;
                if (lane == 0) base = atomicAdd(cnt + 2, __popcll(m));
                base = __shfl(base, 0);
                if (c == 2) list2[base + __popcll(m & (lanebit - 1))] = (t << 17) | (unsigned)(id - CUT1);
            }
        }
    } else {
        // transpose w1 (1024x256 -> 256x1024), then w2 (1024x64 -> 64x1024)
        int i = (bid - NTOK / 256) * 256 + tid;
        if (i < D1 * D) {
            int k = i >> 10, d = i & (D - 1);
            w1T[i] = w1[d * D1 + k];
        } else {
            int j = i - D1 * D;          // j < D2*D by grid sizing
            int k = j >> 10, d = j & (D - 1);
            w2T[j] = w2[d * D2 + k];
        }
    }
}

__global__ __launch_bounds__(256) void k_copy0(
        const float* __restrict__ emb0,
        float* __restrict__ out,
        const int* __restrict__ cnt,
        const unsigned* __restrict__ list0) {
    int n0 = cnt[0];
    for (int r = blockIdx.x; r < n0; r += gridDim.x) {
        unsigned p = list0[r];
        unsigned tok = p >> 17, id = p & 0x1FFFFu;
        const float4* src = (const float4*)(emb0 + (size_t)id * D);
        float4* dst = (float4*)(out + (size_t)tok * D);
        dst[threadIdx.x] = src[threadIdx.x];
    }
}

// Tile: 32 tokens x 256 d-outputs per block; thread = 8 tokens x 4 d.
// blocks [0,4096): cluster 1 (K=256); [4096,8192): cluster 2 (K=64)
__global__ __launch_bounds__(256) void k_gemm(
        const float* __restrict__ emb1,
        const float* __restrict__ emb2,
        const float* __restrict__ b1,
        const float* __restrict__ b2,
        float* __restrict__ out,
        const int* __restrict__ cnt,
        const unsigned* __restrict__ list1,
        const unsigned* __restrict__ list2,
        const float* __restrict__ w1T,
        const float* __restrict__ w2T) {
    __shared__ float As[D1 * 36];   // [k][tok], stride 36 (144B: float4-aligned)
    __shared__ unsigned toks[32];
    __shared__ unsigned lidx[32];

    int bid = blockIdx.x, tid = threadIdx.x;
    bool c1 = bid < 4096;
    int bb = c1 ? bid : bid - 4096;
    int dd = bb & 3, tt = bb >> 2;
    int n = c1 ? cnt[1] : cnt[2];
    int base = tt * 32;
    if (base >= n) return;
    int nt = min(32, n - base);

    const unsigned* list = c1 ? list1 : list2;
    if (tid < nt) {
        unsigned p = list[base + tid];
        toks[tid] = p >> 17;
        lidx[tid] = p & 0x1FFFFu;
    }
    __syncthreads();

    if (c1) {
        // stage 32 rows x 256 floats: thread tid holds k=tid
        for (int i = 0; i < 32; i++) {
            float v = (i < nt) ? emb1[(size_t)lidx[i] * D1 + tid] : 0.f;
            As[tid * 36 + i] = v;
        }
    } else {
        // rows of 64 floats: 4 rows per iteration, coalesced 256B per row
        int k = tid & 63, ii = tid >> 6;
        for (int it = 0; it < 8; it++) {
            int i = it * 4 + ii;
            float v = (i < nt) ? emb2[(size_t)lidx[i] * D2 + k] : 0.f;
            As[k * 36 + i] = v;
        }
    }
    __syncthreads();

    int dl = tid & 63, tg = tid >> 6;        // wave-uniform tg -> As reads broadcast
    int d = dd * 256 + dl * 4;
    const float* wT = c1 ? w1T : w2T;
    int K = c1 ? D1 : D2;

    float acc[8][4];
#pragma unroll
    for (int i = 0; i < 8; i++)
#pragma unroll
        for (int j = 0; j < 4; j++) acc[i][j] = 0.f;

#pragma unroll 4
    for (int k = 0; k < K; k++) {
        float4 w  = *(const float4*)(wT + (size_t)k * D + d);
        float4 a0 = *(const float4*)(&As[k * 36 + tg * 8]);
        float4 a1 = *(const float4*)(&As[k * 36 + tg * 8 + 4]);
        float av[8] = {a0.x, a0.y, a0.z, a0.w, a1.x, a1.y, a1.z, a1.w};
#pragma unroll
        for (int i = 0; i < 8; i++) {
            acc[i][0] += av[i] * w.x;
            acc[i][1] += av[i] * w.y;
            acc[i][2] += av[i] * w.z;
            acc[i][3] += av[i] * w.w;
        }
    }

    float4 bias = *(const float4*)((c1 ? b1 : b2) + d);
#pragma unroll
    for (int i = 0; i < 8; i++) {
        int ti = tg * 8 + i;
        if (ti < nt) {
            float4 o;
            o.x = acc[i][0] + bias.x;
            o.y = acc[i][1] + bias.y;
            o.z = acc[i][2] + bias.z;
            o.w = acc[i][3] + bias.w;
            *(float4*)(out + (size_t)toks[ti] * D + d) = o;
        }
    }
}

extern "C" void kernel_launch(void* const* d_in, const int* in_sizes, int n_in,
                              void* d_out, int out_size, void* d_ws, size_t ws_size,
                              hipStream_t stream) {
    const int*   ids  = (const int*)d_in[0];
    const float* emb0 = (const float*)d_in[1];
    const float* emb1 = (const float*)d_in[2];
    const float* emb2 = (const float*)d_in[3];
    const float* w1   = (const float*)d_in[4];
    const float* b1   = (const float*)d_in[5];
    const float* w2   = (const float*)d_in[6];
    const float* b2   = (const float*)d_in[7];
    float* out = (float*)d_out;

    int* cnt        = (int*)d_ws;
    unsigned* list0 = (unsigned*)(cnt + 64);   // 256 B offset
    unsigned* list1 = list0 + NTOK;
    unsigned* list2 = list1 + NTOK;
    float* w1T      = (float*)(list2 + NTOK);
    float* w2T      = w1T + D1 * D;

    hipLaunchKernelGGL(k_init, dim3(1), dim3(64), 0, stream, cnt);
    // 128 token blocks + 1280 transpose blocks
    hipLaunchKernelGGL(k_classify, dim3(NTOK / 256 + 1280), dim3(256), 0, stream,
                       ids, w1, w2, cnt, list0, list1, list2, w1T, w2T);
    hipLaunchKernelGGL(k_copy0, dim3(2048), dim3(256), 0, stream,
                       emb0, out, cnt, list0);
    hipLaunchKernelGGL(k_gemm, dim3(8192), dim3(256), 0, stream,
                       emb1, emb2, b1, b2, out, cnt, list1, list2, w1T, w2T);
}

// Round 4
// 107.419 us; speedup vs baseline: 4.6115x; 1.3740x over previous
//
#include <hip/hip_runtime.h>

#define CUT0 20000
#define CUT1 60000
#define D    1024
#define D1   256
#define D2   64
#define NTOK 32768

typedef __bf16  bf16x8 __attribute__((ext_vector_type(8)));
typedef float   f32x4  __attribute__((ext_vector_type(4)));

// ws layout:
//   int      cnt[64]                          (n0, n1, n2, pad)
//   unsigned list0[NTOK], list1[NTOK], list2[NTOK]   packed (tok<<17)|local_idx
//   __bf16   w1b[D*D1]   (same [d][k] layout as w1 — IS the MFMA B operand)
//   __bf16   w2b[D*D2]

__global__ void k_init(int* cnt) {
    if (threadIdx.x < 3) cnt[threadIdx.x] = 0;
}

__global__ __launch_bounds__(256) void k_classify(
        const int* __restrict__ ids,
        const float* __restrict__ w1,
        const float* __restrict__ w2,
        int* cnt, unsigned* list0, unsigned* list1, unsigned* list2,
        __bf16* __restrict__ w1b, __bf16* __restrict__ w2b) {
    int bid = blockIdx.x, tid = threadIdx.x;
    if (bid < NTOK / 256) {
        unsigned t = bid * 256 + tid;
        int id = ids[t];
        int lane = tid & 63;
        unsigned long long lanebit = 1ull << lane;
        int c = (id < CUT0) ? 0 : (id < CUT1 ? 1 : 2);
        {
            unsigned long long m = __ballot(c == 0);
            if (m) {
                int base = 0;
                if (lane == 0) base = atomicAdd(cnt + 0, __popcll(m));
                base = __shfl(base, 0);
                if (c == 0) list0[base + __popcll(m & (lanebit - 1))] = (t << 17) | (unsigned)id;
            }
        }
        {
            unsigned long long m = __ballot(c == 1);
            if (m) {
                int base = 0;
                if (lane == 0) base = atomicAdd(cnt + 1, __popcll(m));
                base = __shfl(base, 0);
                if (c == 1) list1[base + __popcll(m & (lanebit - 1))] = (t << 17) | (unsigned)(id - CUT0);
            }
        }
        {
            unsigned long long m = __ballot(c == 2);
            if (m) {
                int base = 0;
                if (lane == 0) base = atomicAdd(cnt + 2, __popcll(m));
                base = __shfl(base, 0);
                if (c == 2) list2[base + __popcll(m & (lanebit - 1))] = (t << 17) | (unsigned)(id - CUT1);
            }
        }
    } else {
        // cast w1 (1024x256) then w2 (1024x64) to bf16, same layout
        int i = (bid - NTOK / 256) * 256 + tid;
        if (i < D1 * D) {
            w1b[i] = (__bf16)w1[i];
        } else {
            int j = i - D1 * D;          // j < D2*D by grid sizing
            w2b[j] = (__bf16)w2[j];
        }
    }
}

__global__ __launch_bounds__(256) void k_copy0(
        const float* __restrict__ emb0,
        float* __restrict__ out,
        const int* __restrict__ cnt,
        const unsigned* __restrict__ list0) {
    int n0 = cnt[0];
    for (int r = blockIdx.x; r < n0; r += gridDim.x) {
        unsigned p = list0[r];
        unsigned tok = p >> 17, id = p & 0x1FFFFu;
        const float4* src = (const float4*)(emb0 + (size_t)id * D);
        float4* dst = (float4*)(out + (size_t)tok * D);
        dst[threadIdx.x] = src[threadIdx.x];
    }
}

// MFMA gemm. Block = 16 tokens x 1024 d; wave wv owns cols [wv*256, wv*256+256).
// Per wave: 16 col-tiles of 16x16, K-loop in steps of 32.
// blocks [0,2048): cluster 1 (K=256); [2048,4096): cluster 2 (K=64)
// A[m][k] = emb_row[m][k] (gathered, fp32->bf16); B[k][n] = wb[n][k] (16B/lane).
// No LDS, no syncthreads.
__global__ __launch_bounds__(256) void k_gemm(
        const float* __restrict__ emb1,
        const float* __restrict__ emb2,
        const float* __restrict__ b1,
        const float* __restrict__ b2,
        float* __restrict__ out,
        const int* __restrict__ cnt,
        const unsigned* __restrict__ list1,
        const unsigned* __restrict__ list2,
        const __bf16* __restrict__ w1b,
        const __bf16* __restrict__ w2b) {
    int bid = blockIdx.x, tid = threadIdx.x;
    bool c1 = bid < 2048;
    int tt = c1 ? bid : bid - 2048;
    int n = c1 ? cnt[1] : cnt[2];
    int base = tt * 16;
    if (base >= n) return;
    int nt = min(16, n - base);

    const unsigned* list = c1 ? list1 : list2;
    const float*    emb  = c1 ? emb1 : emb2;
    const __bf16*   wb   = c1 ? w1b : w2b;
    const float*    bias = c1 ? b1 : b2;
    const int K  = c1 ? D1 : D2;
    const int KS = c1 ? 8 : 2;         // K/32

    int lane = tid & 63;
    int wv   = tid >> 6;
    int col  = lane & 15;              // token-row for A load, col for B/D
    int kg   = lane >> 4;              // k-group 0..3
    int dbase = wv * 256;

    int li = base + col;
    unsigned p = list[li < n ? li : n - 1];
    unsigned lidx = p & 0x1FFFFu;

    f32x4 acc[16];
#pragma unroll
    for (int t = 0; t < 16; t++) acc[t] = (f32x4){0.f, 0.f, 0.f, 0.f};

    const float*  ap = emb + (size_t)lidx * K + kg * 8;
    const __bf16* bp = wb + (size_t)(dbase + col) * K + kg * 8;

    for (int ks = 0; ks < KS; ks++) {
        float4 x = *(const float4*)(ap);
        float4 y = *(const float4*)(ap + 4);
        bf16x8 a;
        a[0] = (__bf16)x.x; a[1] = (__bf16)x.y; a[2] = (__bf16)x.z; a[3] = (__bf16)x.w;
        a[4] = (__bf16)y.x; a[5] = (__bf16)y.y; a[6] = (__bf16)y.z; a[7] = (__bf16)y.w;
#pragma unroll
        for (int t = 0; t < 16; t++) {
            bf16x8 b = *(const bf16x8*)(bp + (size_t)t * 16 * K);
            acc[t] = __builtin_amdgcn_mfma_f32_16x16x32_bf16(a, b, acc[t], 0, 0, 0);
        }
        ap += 32;
        bp += 32;
    }

    float bias_t[16];
#pragma unroll
    for (int t = 0; t < 16; t++) bias_t[t] = bias[dbase + t * 16 + col];

#pragma unroll
    for (int r = 0; r < 4; r++) {
        int m = kg * 4 + r;                    // D row = token slot
        unsigned pm = __shfl(p, m);
        if (m < nt) {
            float* orow = out + (size_t)(pm >> 17) * D + dbase + col;
#pragma unroll
            for (int t = 0; t < 16; t++)
                orow[t * 16] = acc[t][r] + bias_t[t];
        }
    }
}

extern "C" void kernel_launch(void* const* d_in, const int* in_sizes, int n_in,
                              void* d_out, int out_size, void* d_ws, size_t ws_size,
                              hipStream_t stream) {
    const int*   ids  = (const int*)d_in[0];
    const float* emb0 = (const float*)d_in[1];
    const float* emb1 = (const float*)d_in[2];
    const float* emb2 = (const float*)d_in[3];
    const float* w1   = (const float*)d_in[4];
    const float* b1   = (const float*)d_in[5];
    const float* w2   = (const float*)d_in[6];
    const float* b2   = (const float*)d_in[7];
    float* out = (float*)d_out;

    int* cnt        = (int*)d_ws;
    unsigned* list0 = (unsigned*)(cnt + 64);   // 256 B offset
    unsigned* list1 = list0 + NTOK;
    unsigned* list2 = list1 + NTOK;
    __bf16* w1b     = (__bf16*)(list2 + NTOK);
    __bf16* w2b     = w1b + (size_t)D * D1;

    hipLaunchKernelGGL(k_init, dim3(1), dim3(64), 0, stream, cnt);
    // 128 token blocks + 1280 w-cast blocks ((262144+65536)/256)
    hipLaunchKernelGGL(k_classify, dim3(NTOK / 256 + 1280), dim3(256), 0, stream,
                       ids, w1, w2, cnt, list0, list1, list2, w1b, w2b);
    hipLaunchKernelGGL(k_copy0, dim3(2048), dim3(256), 0, stream,
                       emb0, out, cnt, list0);
    hipLaunchKernelGGL(k_gemm, dim3(4096), dim3(256), 0, stream,
                       emb1, emb2, b1, b2, out, cnt, list1, list2, w1b, w2b);
}